// Round 1
// baseline (154.507 us; speedup 1.0000x reference)
//
#include <hip/hip_runtime.h>
#include <math.h>

// Problem constants (from reference): x [512,256,12] fp32, codebook [512,12] fp32.
// Outputs (concatenated fp32): quantized_st [512*256*12], indices-as-float [512*256], loss [1].
namespace {
constexpr int KCB   = 512;            // codebook size
constexpr int DIM   = 12;             // latent dim
constexpr int NTOK  = 512 * 256;      // 131072 tokens
constexpr int QSIZE = NTOK * DIM;     // 1572864

// Pack codebook into 16-float (64B) rows in workspace: w[0..11], w2, pad.
// Precomputing w2 avoids 12 extra FMAs per (token,k) in the hot loop, and the
// 64B row lets the main kernel fetch one code with uniform s_load_dwordx4 x4.
__global__ __launch_bounds__(256) void pack_cb(const float* __restrict__ cb,
                                               float* __restrict__ pk) {
    int k = blockIdx.x * blockDim.x + threadIdx.x;
    if (k >= KCB) return;
    float w[DIM];
#pragma unroll
    for (int d = 0; d < DIM; ++d) w[d] = cb[k * DIM + d];
    float w2 = 0.f;
#pragma unroll
    for (int d = 0; d < DIM; ++d) w2 += w[d] * w[d];
#pragma unroll
    for (int d = 0; d < DIM; ++d) pk[k * 16 + d] = w[d];
    pk[k * 16 + 12] = w2;
    pk[k * 16 + 13] = 0.f;
    pk[k * 16 + 14] = 0.f;
    pk[k * 16 + 15] = 0.f;
}

// One thread = one token. k-loop reads the packed codebook with wave-uniform
// addresses -> compiler scalarizes to s_load (SGPR broadcast), so the inner
// loop is pure v_fma_f32 + argmin tracking. Numerics mimic the numpy ref:
//   d = fl( fl(x2 - 2*xw) + w2 )   [fmaf(-2,xw,x2) == separate rounding, 2*xw exact]
// first-occurrence argmin via strict <.
__global__ __launch_bounds__(256) void vq_main(const float* __restrict__ x,
                                               const float* __restrict__ cb,
                                               const float4* __restrict__ pk,
                                               float* __restrict__ out) {
    const int t = blockIdx.x * 256 + threadIdx.x;   // grid exactly covers NTOK

    // token vector: 12 floats = 3 x float4 (48B rows are 16B aligned)
    const float4* xp = (const float4*)(x + (size_t)t * DIM);
    float4 xa = xp[0], xb = xp[1], xc = xp[2];
    float xs[DIM] = {xa.x, xa.y, xa.z, xa.w,
                     xb.x, xb.y, xb.z, xb.w,
                     xc.x, xc.y, xc.z, xc.w};

    float x2 = 0.f;
#pragma unroll
    for (int d = 0; d < DIM; ++d) x2 = fmaf(xs[d], xs[d], x2);

    float best = INFINITY;
    int bi = 0;
#pragma unroll 4
    for (int k = 0; k < KCB; ++k) {
        // 64B packed row, uniform address -> s_load into SGPRs
        float4 c0 = pk[k * 4 + 0];
        float4 c1 = pk[k * 4 + 1];
        float4 c2 = pk[k * 4 + 2];
        float4 c3 = pk[k * 4 + 3];   // c3.x = w2[k]
        float xw = 0.f;
        xw = fmaf(xs[0],  c0.x, xw);
        xw = fmaf(xs[1],  c0.y, xw);
        xw = fmaf(xs[2],  c0.z, xw);
        xw = fmaf(xs[3],  c0.w, xw);
        xw = fmaf(xs[4],  c1.x, xw);
        xw = fmaf(xs[5],  c1.y, xw);
        xw = fmaf(xs[6],  c1.z, xw);
        xw = fmaf(xs[7],  c1.w, xw);
        xw = fmaf(xs[8],  c2.x, xw);
        xw = fmaf(xs[9],  c2.y, xw);
        xw = fmaf(xs[10], c2.z, xw);
        xw = fmaf(xs[11], c2.w, xw);
        float dsc = fmaf(-2.f, xw, x2) + c3.x;
        bool cnd = dsc < best;          // strict < => first-min index, matches np.argmin
        best = cnd ? dsc : best;
        bi   = cnd ? k : bi;
    }

    // quantized_st = x + (q - x), mirroring the reference's elementwise rounding
    const float4* wrow = (const float4*)(cb + (size_t)bi * DIM);  // 48B-aligned
    float4 q0 = wrow[0], q1 = wrow[1], q2 = wrow[2];
    float qs[DIM] = {q0.x, q0.y, q0.z, q0.w,
                     q1.x, q1.y, q1.z, q1.w,
                     q2.x, q2.y, q2.z, q2.w};
    float4* qo = (float4*)(out + (size_t)t * DIM);
    float4 r0, r1, r2;
    r0.x = xs[0] + (qs[0] - xs[0]);   r0.y = xs[1] + (qs[1] - xs[1]);
    r0.z = xs[2] + (qs[2] - xs[2]);   r0.w = xs[3] + (qs[3] - xs[3]);
    r1.x = xs[4] + (qs[4] - xs[4]);   r1.y = xs[5] + (qs[5] - xs[5]);
    r1.z = xs[6] + (qs[6] - xs[6]);   r1.w = xs[7] + (qs[7] - xs[7]);
    r2.x = xs[8] + (qs[8] - xs[8]);   r2.y = xs[9] + (qs[9] - xs[9]);
    r2.z = xs[10] + (qs[10] - xs[10]); r2.w = xs[11] + (qs[11] - xs[11]);
    qo[0] = r0; qo[1] = r1; qo[2] = r2;

    // indices as float (d_out is a single fp32 buffer)
    out[QSIZE + t] = (float)bi;

    // loss: sum_d (q-x)^2 == best (same exact value, fp32-rounded differently by
    // ~1e-8 relative -- far under the ~2% threshold). Scale then block-reduce.
    float ls = best * (1.25f / (float)QSIZE);
#pragma unroll
    for (int off = 32; off > 0; off >>= 1) ls += __shfl_down(ls, off);
    __shared__ float red[4];
    int lane = threadIdx.x & 63;
    int wid  = threadIdx.x >> 6;
    if (lane == 0) red[wid] = ls;
    __syncthreads();
    if (threadIdx.x == 0) {
        float s = (red[0] + red[1]) + (red[2] + red[3]);
        atomicAdd(out + QSIZE + NTOK, s);
    }
}
} // namespace

extern "C" void kernel_launch(void* const* d_in, const int* in_sizes, int n_in,
                              void* d_out, int out_size, void* d_ws, size_t ws_size,
                              hipStream_t stream) {
    const float* x  = (const float*)d_in[0];
    const float* cb = (const float*)d_in[1];
    float* out = (float*)d_out;
    float* pk  = (float*)d_ws;   // 512*16*4 = 32 KiB of workspace

    // loss accumulator must start at 0 (harness poisons d_out with 0xAA)
    hipMemsetAsync(out + QSIZE + NTOK, 0, sizeof(float), stream);
    pack_cb<<<2, 256, 0, stream>>>(cb, pk);
    vq_main<<<NTOK / 256, 256, 0, stream>>>(x, cb, (const float4*)pk, out);
}

// Round 2
// 109.480 us; speedup vs baseline: 1.4113x; 1.4113x over previous
//
#include <hip/hip_runtime.h>
#include <math.h>

// VQ quantizer: x [512,256,12] fp32, codebook [512,12] fp32.
// Outputs (concatenated fp32): quantized_st [512*256*12], indices-as-float [512*256], loss [1].
namespace {
constexpr int KCB   = 512;            // codebook size
constexpr int DIM   = 12;             // latent dim
constexpr int NTOK  = 512 * 256;      // 131072 tokens
constexpr int QSIZE = NTOK * DIM;     // 1572864
constexpr int NSPLIT = 4;             // k-chunks per token (one per wave in a block)
constexpr int KCHUNK = KCB / NSPLIT;  // 128
constexpr int TOKS_PER_BLOCK = 64;    // one wave's worth of tokens

// Pack codebook into 16-float (64B) rows: w[0..11], w2, pad. Also zero the
// loss accumulator (harness re-poisons d_out to 0xAA before every launch).
__global__ __launch_bounds__(256) void pack_cb(const float* __restrict__ cb,
                                               float* __restrict__ pk,
                                               float* __restrict__ out) {
    int k = blockIdx.x * blockDim.x + threadIdx.x;
    if (k == 0) out[QSIZE + NTOK] = 0.f;   // loss slot, before vq_main (stream-ordered)
    if (k >= KCB) return;
    float w[DIM];
#pragma unroll
    for (int d = 0; d < DIM; ++d) w[d] = cb[k * DIM + d];
    float w2 = 0.f;
#pragma unroll
    for (int d = 0; d < DIM; ++d) w2 += w[d] * w[d];
#pragma unroll
    for (int d = 0; d < DIM; ++d) pk[k * 16 + d] = w[d];
    pk[k * 16 + 12] = w2;
    pk[k * 16 + 13] = 0.f;
    pk[k * 16 + 14] = 0.f;
    pk[k * 16 + 15] = 0.f;
}

// Block = 64 tokens x 4 k-splits. Wave s scans codes [s*128, (s+1)*128) for
// its 64 tokens; cross-wave argmin combined via packed u64 (score,k) min in
// LDS — exact first-occurrence argmin (smallest k among equal scores).
// Numerics are bit-identical to the round-1 kernel that matched numpy
// (same fmaf dot order per code; splitting k doesn't change per-code math).
__global__ __launch_bounds__(256, 8) void vq_main(const float* __restrict__ x,
                                                  const float* __restrict__ cb,
                                                  const float4* __restrict__ pk,
                                                  float* __restrict__ out) {
    const int tid  = threadIdx.x;
    const int lane = tid & 63;
    // wave id == k-split id. readfirstlane makes it provably wave-uniform so
    // codebook indexing stays on the scalar-load pipe (s_load, SGPR broadcast).
    const int s = __builtin_amdgcn_readfirstlane(tid >> 6);
    const int t = blockIdx.x * TOKS_PER_BLOCK + lane;

    const float4* xp = (const float4*)(x + (size_t)t * DIM);
    float4 xa = xp[0], xb = xp[1], xc = xp[2];
    float xs[DIM] = {xa.x, xa.y, xa.z, xa.w,
                     xb.x, xb.y, xb.z, xb.w,
                     xc.x, xc.y, xc.z, xc.w};

    float x2 = 0.f;
#pragma unroll
    for (int d = 0; d < DIM; ++d) x2 = fmaf(xs[d], xs[d], x2);

    float best = INFINITY;
    int bi = 0;
    const int k0 = s * KCHUNK;
#pragma unroll 4
    for (int kk = 0; kk < KCHUNK; ++kk) {
        const int k = k0 + kk;                 // wave-uniform -> s_load_dwordx4 x4
        float4 c0 = pk[k * 4 + 0];
        float4 c1 = pk[k * 4 + 1];
        float4 c2 = pk[k * 4 + 2];
        float4 c3 = pk[k * 4 + 3];             // c3.x = w2[k]
        float xw = 0.f;
        xw = fmaf(xs[0],  c0.x, xw);
        xw = fmaf(xs[1],  c0.y, xw);
        xw = fmaf(xs[2],  c0.z, xw);
        xw = fmaf(xs[3],  c0.w, xw);
        xw = fmaf(xs[4],  c1.x, xw);
        xw = fmaf(xs[5],  c1.y, xw);
        xw = fmaf(xs[6],  c1.z, xw);
        xw = fmaf(xs[7],  c1.w, xw);
        xw = fmaf(xs[8],  c2.x, xw);
        xw = fmaf(xs[9],  c2.y, xw);
        xw = fmaf(xs[10], c2.z, xw);
        xw = fmaf(xs[11], c2.w, xw);
        float dsc = fmaf(-2.f, xw, x2) + c3.x; // same rounding as round-1 (matched np)
        bool cnd = dsc < best;                 // strict < => first occurrence in chunk
        best = cnd ? dsc : best;
        bi   = cnd ? k : bi;
    }

    // Pack (score,k) into u64 so unsigned-min == lexicographic (score, k) min.
    unsigned su = __float_as_uint(best);
    su = (su & 0x80000000u) ? ~su : (su | 0x80000000u);  // monotone float->uint map
    unsigned long long key = ((unsigned long long)su << 32) | (unsigned)bi;

    __shared__ unsigned long long red[NSPLIT][TOKS_PER_BLOCK];
    red[s][lane] = key;
    __syncthreads();

    if (s == 0) {
        unsigned long long m0 = red[0][lane], m1 = red[1][lane];
        unsigned long long m2 = red[2][lane], m3 = red[3][lane];
        unsigned long long a = m0 < m1 ? m0 : m1;
        unsigned long long b = m2 < m3 ? m2 : m3;
        unsigned long long m = a < b ? a : b;
        const int bid = (int)(m & 0xffffffffULL);
        unsigned eu = (unsigned)(m >> 32);
        unsigned orig = (eu & 0x80000000u) ? (eu ^ 0x80000000u) : ~eu;
        const float bsc = __uint_as_float(orig);

        // quantized_st = x + (q - x) elementwise (mirrors reference rounding)
        const float4* wrow = (const float4*)(cb + (size_t)bid * DIM);
        float4 q0 = wrow[0], q1 = wrow[1], q2 = wrow[2];
        float qs[DIM] = {q0.x, q0.y, q0.z, q0.w,
                         q1.x, q1.y, q1.z, q1.w,
                         q2.x, q2.y, q2.z, q2.w};
        float4* qo = (float4*)(out + (size_t)t * DIM);
        float4 r0, r1, r2;
        r0.x = xs[0] + (qs[0] - xs[0]);    r0.y = xs[1] + (qs[1] - xs[1]);
        r0.z = xs[2] + (qs[2] - xs[2]);    r0.w = xs[3] + (qs[3] - xs[3]);
        r1.x = xs[4] + (qs[4] - xs[4]);    r1.y = xs[5] + (qs[5] - xs[5]);
        r1.z = xs[6] + (qs[6] - xs[6]);    r1.w = xs[7] + (qs[7] - xs[7]);
        r2.x = xs[8] + (qs[8] - xs[8]);    r2.y = xs[9] + (qs[9] - xs[9]);
        r2.z = xs[10] + (qs[10] - xs[10]); r2.w = xs[11] + (qs[11] - xs[11]);
        qo[0] = r0; qo[1] = r1; qo[2] = r2;

        out[QSIZE + t] = (float)bid;

        // loss: sum_d(q-x)^2 == best score (fp-rounded ~1e-8 apart; thr ~2%)
        float ls = bsc * (1.25f / (float)QSIZE);
#pragma unroll
        for (int off = 32; off > 0; off >>= 1) ls += __shfl_down(ls, off);
        if (lane == 0) atomicAdd(out + QSIZE + NTOK, ls);
    }
}
} // namespace

extern "C" void kernel_launch(void* const* d_in, const int* in_sizes, int n_in,
                              void* d_out, int out_size, void* d_ws, size_t ws_size,
                              hipStream_t stream) {
    const float* x  = (const float*)d_in[0];
    const float* cb = (const float*)d_in[1];
    float* out = (float*)d_out;
    float* pk  = (float*)d_ws;   // 512*16*4 = 32 KiB of workspace

    pack_cb<<<2, 256, 0, stream>>>(cb, pk, out);
    vq_main<<<NTOK / TOKS_PER_BLOCK, 256, 0, stream>>>(x, cb, (const float4*)pk, out);
}